// Round 9
// baseline (991.302 us; speedup 1.0000x reference)
//
#include <hip/hip_runtime.h>

// GCN autoencoder on MI355X (gfx950).
// bf16-MFMA GEMM (BK=64, global_load_lds, counted vmcnt, LDS-staged epilogue)
// + deep-unrolled gather agg (at fabric roofline).
// N=50000, E=800000, F=500, H=256, C=10 (derived at runtime).

typedef __attribute__((ext_vector_type(8))) short short8;           // 8 bf16
typedef __attribute__((ext_vector_type(4))) float f32x4;            // MFMA acc

// ---------------------------------------------------------------- helpers

__device__ __forceinline__ float b2f(unsigned short u) {
  union { unsigned int i; float f; } v; v.i = ((unsigned int)u) << 16; return v.f;
}
__device__ __forceinline__ unsigned short f2b(float f) {  // RNE
  union { float f; unsigned int i; } v; v.f = f;
  unsigned int r = v.i + 0x7FFFu + ((v.i >> 16) & 1u);
  return (unsigned short)(r >> 16);
}
__device__ __forceinline__ void up2(unsigned int u, float& a, float& b) {
  union { unsigned int i; float f; } x, y;
  x.i = u << 16; y.i = u & 0xffff0000u;
  a = x.f; b = y.f;
}
__device__ __forceinline__ float i2f(int i) {
  union { int i; float f; } v; v.i = i; return v.f;
}

// async global->LDS, 16B per lane; dest = lds_base(wave-uniform) + lane*16
__device__ __forceinline__ void gload16(const void* g, void* l) {
  __builtin_amdgcn_global_load_lds(
      (const __attribute__((address_space(1))) unsigned int*)g,
      (__attribute__((address_space(3))) unsigned int*)l, 16, 0, 0);
}

// ---------------------------------------------------------------- preproc

__global__ void k_zero_int(int* __restrict__ p, int n) {
  int i = blockIdx.x * blockDim.x + threadIdx.x;
  if (i < n) p[i] = 0;
}

__global__ void k_deg(const int* __restrict__ dst, int* __restrict__ deg, int E) {
  int i = blockIdx.x * blockDim.x + threadIdx.x;
  if (i < E) atomicAdd(&deg[dst[i]], 1);
}

// 3-pass parallel scan (n up to 256*1024)
__global__ void k_scan1(const int* __restrict__ deg, int* __restrict__ part, int n) {
  __shared__ int sh[256];
  int i = blockIdx.x * 256 + threadIdx.x;
  sh[threadIdx.x] = (i < n) ? deg[i] : 0;
  __syncthreads();
  for (int o = 128; o > 0; o >>= 1) {
    if (threadIdx.x < o) sh[threadIdx.x] += sh[threadIdx.x + o];
    __syncthreads();
  }
  if (threadIdx.x == 0) part[blockIdx.x] = sh[0];
}

__global__ __launch_bounds__(1024) void k_scan2(int* __restrict__ part, int nb) {
  __shared__ int sh[1024];
  int t = threadIdx.x;
  int v = (t < nb) ? part[t] : 0;
  sh[t] = v;
  __syncthreads();
  for (int off = 1; off < 1024; off <<= 1) {
    int u = (t >= off) ? sh[t - off] : 0;
    __syncthreads();
    sh[t] += u;
    __syncthreads();
  }
  if (t < nb) part[t] = sh[t] - v;  // exclusive
}

__global__ void k_scan3(const int* __restrict__ deg, const int* __restrict__ part,
                        int* __restrict__ row_start, int* __restrict__ cursor,
                        float* __restrict__ dinv, int n) {
  __shared__ int sh[256];
  int t = threadIdx.x;
  int i = blockIdx.x * 256 + t;
  int v = (i < n) ? deg[i] : 0;
  sh[t] = v;
  __syncthreads();
  for (int off = 1; off < 256; off <<= 1) {
    int u = (t >= off) ? sh[t - off] : 0;
    __syncthreads();
    sh[t] += u;
    __syncthreads();
  }
  if (i < n) {
    int excl = part[blockIdx.x] + sh[t] - v;
    row_start[i] = excl;
    cursor[i] = excl;
    dinv[i] = rsqrtf((float)v + 1.0f);
    if (i == n - 1) row_start[n] = excl + v;
  }
}

// fused CSR entries: .x = src index, .y = float bits of norm
__global__ void k_fill_csr(const int* __restrict__ src, const int* __restrict__ dst,
                           const float* __restrict__ dinv, int* __restrict__ cursor,
                           int2* __restrict__ csr_ent, int E) {
  int e = blockIdx.x * blockDim.x + threadIdx.x;
  if (e < E) {
    int d = dst[e];
    int s = src[e];
    int pos = atomicAdd(&cursor[d], 1);
    float nrm = dinv[s] * dinv[d];
    csr_ent[pos] = make_int2(s, __float_as_int(nrm));
  }
}

// x[N][F] fp32 -> xb[N][Fp] bf16, zero-padded cols
__global__ void k_cvt_pad(const float* __restrict__ in, unsigned short* __restrict__ out,
                          int N, int F, int Fp) {
  int idx = blockIdx.x * blockDim.x + threadIdx.x;
  int perRow = Fp >> 3;
  int row = idx / perRow;
  int c = (idx - row * perRow) << 3;
  if (row >= N) return;
  unsigned short o[8];
  if (c + 8 <= F) {
    const float* p = in + (size_t)row * F + c;
    #pragma unroll
    for (int e = 0; e < 8; ++e) o[e] = f2b(p[e]);
  } else {
    #pragma unroll
    for (int e = 0; e < 8; ++e) {
      int cc = c + e;
      o[e] = (cc < F) ? f2b(in[(size_t)row * F + cc]) : (unsigned short)0;
    }
  }
  *(short8*)(out + (size_t)row * Fp + c) = *(short8*)o;
}

// all 8 weights: W[K][Nd] fp32 -> Wt[Ndp][Kp] bf16 (transposed, zero-padded)
struct WtPack {
  const float* W[8];
  unsigned short* Wt[8];
  int K[8], Nd[8], Kp[8], Ndp[8];
};

__global__ void k_wt_all(WtPack p) {
  int l = blockIdx.y;
  int idx = blockIdx.x * blockDim.x + threadIdx.x;
  int Kp = p.Kp[l], Ndp = p.Ndp[l];
  if (idx >= Kp * Ndp) return;
  int n = idx / Kp, k = idx - n * Kp;
  unsigned short v = 0;
  if (n < p.Nd[l] && k < p.K[l]) v = f2b(p.W[l][(size_t)k * p.Nd[l] + n]);
  p.Wt[l][idx] = v;
}

// ---------------------------------------------------------------- GEMM
// C[M,Nd] = A[M,Kp] @ Bt^T, A bf16 [M][lda], Bt bf16 [Ndp][Kp], padded
// (Ndp%128==0, Kp%64==0). 128x128 tile, 4 waves (2x2), BK=64 (2 k-halves of
// mfma_f32_16x16x32_bf16). global_load_lds staging, 2-deep, counted vmcnt(8).
// 16B-slot swizzle: physical slot = k_slot ^ (row&7), applied at the global
// source AND the ds_read (both-sides rule). LDS-staged vectorized epilogue.
// LDS layout: A buffers at smem+0 / smem+8192, B at smem+16384 / smem+24576.

__global__ __launch_bounds__(256) void gemm_bf16(
    const unsigned short* __restrict__ A,
    const unsigned short* __restrict__ Bt,
    const float* __restrict__ bias,     // nullable, [Nd]
    float* __restrict__ Cf, int ldcf,   // nullable
    unsigned short* __restrict__ Cb, int ldcb,  // nullable
    int M, int Kp, int Nd, int lda, int relu) {
  __shared__ __attribute__((aligned(16))) unsigned short smem[32768];  // 64KB

  const int bm = blockIdx.x * 128;
  const int bn = blockIdx.y * 128;
  const int tid = threadIdx.x;
  const int wid = tid >> 6;
  const int lane = tid & 63;

  // staging: wave wid fills rows [wid*32, wid*32+32); gload j covers 8 rows.
  // lane: row-in-chunk = lane>>3, physical slot = lane&7,
  // source k-slot = (lane&7) ^ (row&7) = (lane&7) ^ (lane>>3).
  const unsigned short* srcA[4];
  const unsigned short* srcB[4];
  #pragma unroll
  for (int j = 0; j < 4; ++j) {
    int r_st = wid * 32 + j * 8 + (lane >> 3);
    int sw = (lane & 7) ^ (lane >> 3);
    int gm = bm + r_st; if (gm > M - 1) gm = M - 1;   // clamp: dup rows unused
    srcA[j] = A + (size_t)gm * lda + sw * 8;
    int gn = bn + r_st;                                // < Ndp (padded)
    srcB[j] = Bt + (size_t)gn * Kp + sw * 8;
  }

  const int wr = wid >> 1, wc = wid & 1;
  const int lrow = lane & 15;
  const int kgrp = lane >> 4;
  const int rA = wr * 64 + lrow;
  const int rB = wc * 64 + lrow;
  // swizzled 16B-slot element offsets for k-half 0/1
  int sOff[2];
  #pragma unroll
  for (int kh = 0; kh < 2; ++kh)
    sOff[kh] = ((kh * 4 + kgrp) ^ (lrow & 7)) * 8;

  f32x4 acc[4][4];
  #pragma unroll
  for (int i = 0; i < 4; ++i)
    #pragma unroll
    for (int j = 0; j < 4; ++j) acc[i][j] = (f32x4){0.f, 0.f, 0.f, 0.f};

  auto stage = [&](int buf, int k0) {
    unsigned short* As = smem + buf * 8192;
    unsigned short* Bs = smem + 16384 + buf * 8192;
    #pragma unroll
    for (int j = 0; j < 4; ++j)
      gload16(srcA[j] + k0, As + (wid * 32 + j * 8) * 64);
    #pragma unroll
    for (int j = 0; j < 4; ++j)
      gload16(srcB[j] + k0, Bs + (wid * 32 + j * 8) * 64);
  };

  const int nt = Kp >> 6;
  stage(0, 0);
  if (nt > 1) stage(1, 64);
  int cur = 0;
  for (int t = 0; t < nt; ++t) {
    if (t + 1 < nt) asm volatile("s_waitcnt vmcnt(8)\n\ts_barrier" ::: "memory");
    else            asm volatile("s_waitcnt vmcnt(0)\n\ts_barrier" ::: "memory");

    const unsigned short* pA = smem + cur * 8192;
    const unsigned short* pB = smem + 16384 + cur * 8192;
    short8 a[2][4], b[2][4];
    #pragma unroll
    for (int kh = 0; kh < 2; ++kh) {
      #pragma unroll
      for (int mi = 0; mi < 4; ++mi)
        a[kh][mi] = *(const short8*)(pA + (rA + mi * 16) * 64 + sOff[kh]);
      #pragma unroll
      for (int nj = 0; nj < 4; ++nj)
        b[kh][nj] = *(const short8*)(pB + (rB + nj * 16) * 64 + sOff[kh]);
    }

    asm volatile("s_waitcnt lgkmcnt(0)\n\ts_barrier" ::: "memory");
    __builtin_amdgcn_sched_barrier(0);

    if (t + 2 < nt) stage(cur, (t + 2) * 64);

    #pragma unroll
    for (int kh = 0; kh < 2; ++kh)
      #pragma unroll
      for (int mi = 0; mi < 4; ++mi)
        #pragma unroll
        for (int nj = 0; nj < 4; ++nj)
          acc[mi][nj] = __builtin_amdgcn_mfma_f32_16x16x32_bf16(
              a[kh][mi], b[kh][nj], acc[mi][nj], 0, 0, 0);
    cur ^= 1;
  }

  // ---- epilogue. Frag D: row = 4*kgrp + rr, col = lrow (within 16x16).
  const int orow = bm + wr * 64;
  const int ocol = bn + wc * 64;
  float bv[4];
  #pragma unroll
  for (int nj = 0; nj < 4; ++nj) {
    int gn = ocol + nj * 16 + lrow;
    bv[nj] = (bias && gn < Nd) ? bias[gn] : 0.f;
  }

  if (Nd >= 128) {
    // all K-loop ds_reads retired before last barrier -> smem reusable
    if (Cb) {
      unsigned short* Lb = smem;  // [128][128] bf16 = 32KB
      #pragma unroll
      for (int mi = 0; mi < 4; ++mi)
        #pragma unroll
        for (int rr = 0; rr < 4; ++rr) {
          int row = wr * 64 + mi * 16 + 4 * kgrp + rr;
          #pragma unroll
          for (int nj = 0; nj < 4; ++nj) {
            float v = acc[mi][nj][rr] + bv[nj];
            if (relu) v = fmaxf(v, 0.f);
            Lb[row * 128 + wc * 64 + nj * 16 + lrow] = f2b(v);
          }
        }
      __syncthreads();
      int r = tid >> 1, hh = tid & 1;
      int gm = bm + r;
      if (gm < M) {
        const short8* sp = (const short8*)(Lb + r * 128 + hh * 64);
        unsigned short* dp = Cb + (size_t)gm * ldcb + bn + hh * 64;
        #pragma unroll
        for (int c = 0; c < 8; ++c) *(short8*)(dp + c * 8) = sp[c];
      }
    } else if (Cf) {
      float* Lf = (float*)smem;   // [128][128] fp32 = 64KB
      #pragma unroll
      for (int mi = 0; mi < 4; ++mi)
        #pragma unroll
        for (int rr = 0; rr < 4; ++rr) {
          int row = wr * 64 + mi * 16 + 4 * kgrp + rr;
          #pragma unroll
          for (int nj = 0; nj < 4; ++nj) {
            float v = acc[mi][nj][rr] + bv[nj];
            if (relu) v = fmaxf(v, 0.f);
            Lf[row * 128 + wc * 64 + nj * 16 + lrow] = v;
          }
        }
      __syncthreads();
      int r = tid >> 1, hh = tid & 1;
      int gm = bm + r;
      if (gm < M) {
        const float* sp = Lf + r * 128 + hh * 64;
        float* dp = Cf + (size_t)gm * ldcf;
        #pragma unroll
        for (int c = 0; c < 16; ++c) {
          int col = bn + hh * 64 + c * 4;
          if (col + 4 <= Nd) {
            __builtin_nontemporal_store(*(const f32x4*)(sp + c * 4),
                                        (f32x4*)(dp + col));
          } else {
            #pragma unroll
            for (int e = 0; e < 4; ++e)
              if (col + e < Nd) dp[col + e] = sp[c * 4 + e];
          }
        }
      }
    }
  } else {
    // narrow-Nd scalar path (zen, Nd=10)
    #pragma unroll
    for (int mi = 0; mi < 4; ++mi) {
      #pragma unroll
      for (int rr = 0; rr < 4; ++rr) {
        int gm = orow + mi * 16 + 4 * kgrp + rr;
        if (gm >= M) continue;
        #pragma unroll
        for (int nj = 0; nj < 4; ++nj) {
          int gn = ocol + nj * 16 + lrow;
          if (gn >= Nd) continue;
          float v = acc[mi][nj][rr] + bv[nj];
          if (relu) v = fmaxf(v, 0.f);
          if (Cf) __builtin_nontemporal_store(v, &Cf[(size_t)gm * ldcf + gn]);
          if (Cb) Cb[(size_t)gm * ldcb + gn] = f2b(v);
        }
      }
    }
  }
}

// ---------------------------------------------------------------- aggregation
// Wave per node; two 32-lane halves, each gathers its own edges at 16B/lane.
// 16 edges per main trip (8 per half). Fused int2 CSR entries, NT-loaded.
// Cross-half combine via shfl_xor(32). half0 stores bf16 mirror; half1 fp32 NT.

__global__ __launch_bounds__(256) void agg_wave(
    const unsigned short* __restrict__ h,
    const int* __restrict__ row_start, const int2* __restrict__ csr_ent,
    const float* __restrict__ dinv,
    const float* __restrict__ bias,      // nullable
    float* __restrict__ Of,              // nullable
    unsigned short* __restrict__ Ob,     // nullable
    int N, int relu) {
  const int w = threadIdx.x >> 6;
  const int lane = threadIdx.x & 63;
  const int i = blockIdx.x * 4 + w;
  if (i >= N) return;
  const int half = lane >> 5;
  const int hl = lane & 31;
  const int f0 = hl * 8;

  float acc[8];
  if (half == 0) {
    float sn = dinv[i]; sn *= sn;
    short8 hv = *(const short8*)(h + ((size_t)i << 8) + f0);
    #pragma unroll
    for (int j = 0; j < 8; ++j) acc[j] = b2f(((const unsigned short*)&hv)[j]) * sn;
  } else if (bias) {
    #pragma unroll
    for (int j = 0; j < 8; ++j) acc[j] = bias[f0 + j];
  } else {
    #pragma unroll
    for (int j = 0; j < 8; ++j) acc[j] = 0.f;
  }

  int s = row_start[i];
  const int s1 = row_start[i + 1];

  // main: 16 edges per trip (8 per half) -> 8 gathers in flight per lane
  for (; s + 16 <= s1; s += 16) {
    long long pe[8];
    #pragma unroll
    for (int k = 0; k < 8; ++k)
      pe[k] = __builtin_nontemporal_load((const long long*)(csr_ent + s + 2 * k + half));
    short8 ve[8];
    #pragma unroll
    for (int k = 0; k < 8; ++k)
      ve[k] = *(const short8*)(h + ((size_t)(int)pe[k] << 8) + f0);
    #pragma unroll
    for (int k = 0; k < 8; ++k) {
      float wt = i2f((int)(pe[k] >> 32));
      #pragma unroll
      for (int j = 0; j < 8; ++j)
        acc[j] = fmaf(b2f(((const unsigned short*)&ve[k])[j]), wt, acc[j]);
    }
  }
  // 8 edges (4 per half)
  for (; s + 8 <= s1; s += 8) {
    long long pe[4];
    #pragma unroll
    for (int k = 0; k < 4; ++k)
      pe[k] = __builtin_nontemporal_load((const long long*)(csr_ent + s + 2 * k + half));
    short8 ve[4];
    #pragma unroll
    for (int k = 0; k < 4; ++k)
      ve[k] = *(const short8*)(h + ((size_t)(int)pe[k] << 8) + f0);
    #pragma unroll
    for (int k = 0; k < 4; ++k) {
      float wt = i2f((int)(pe[k] >> 32));
      #pragma unroll
      for (int j = 0; j < 8; ++j)
        acc[j] = fmaf(b2f(((const unsigned short*)&ve[k])[j]), wt, acc[j]);
    }
  }
  // 4 edges (2 per half)
  for (; s + 4 <= s1; s += 4) {
    long long p0 = __builtin_nontemporal_load((const long long*)(csr_ent + s + half));
    long long p1 = __builtin_nontemporal_load((const long long*)(csr_ent + s + 2 + half));
    short8 v0 = *(const short8*)(h + ((size_t)(int)p0 << 8) + f0);
    short8 v1 = *(const short8*)(h + ((size_t)(int)p1 << 8) + f0);
    float w0 = i2f((int)(p0 >> 32)), w1 = i2f((int)(p1 >> 32));
    #pragma unroll
    for (int j = 0; j < 8; ++j)
      acc[j] = fmaf(b2f(((const unsigned short*)&v0)[j]), w0, acc[j]);
    #pragma unroll
    for (int j = 0; j < 8; ++j)
      acc[j] = fmaf(b2f(((const unsigned short*)&v1)[j]), w1, acc[j]);
  }
  // predicated pairs
  for (; s < s1; s += 2) {
    int e = s + half;
    bool valid = e < s1;
    long long p0 = valid
        ? __builtin_nontemporal_load((const long long*)(csr_ent + e)) : 0ll;
    short8 vv = *(const short8*)(h + ((size_t)(int)p0 << 8) + f0);
    float wt = i2f((int)(p0 >> 32));
    #pragma unroll
    for (int j = 0; j < 8; ++j)
      acc[j] = fmaf(b2f(((const unsigned short*)&vv)[j]), wt, acc[j]);
  }

  #pragma unroll
  for (int j = 0; j < 8; ++j) acc[j] += __shfl_xor(acc[j], 32, 64);
  if (relu) {
    #pragma unroll
    for (int j = 0; j < 8; ++j) acc[j] = fmaxf(acc[j], 0.f);
  }

  size_t o = ((size_t)i << 8) + f0;
  if (half == 0) {
    if (Ob) {
      unsigned short ob[8];
      #pragma unroll
      for (int j = 0; j < 8; ++j) ob[j] = f2b(acc[j]);
      *(short8*)(Ob + o) = *(short8*)ob;
    }
  } else if (Of) {
    f32x4 lo = {acc[0], acc[1], acc[2], acc[3]};
    f32x4 hi = {acc[4], acc[5], acc[6], acc[7]};
    __builtin_nontemporal_store(lo, (f32x4*)(Of + o));
    __builtin_nontemporal_store(hi, (f32x4*)(Of + o + 4));
  }
}

// Code-path aggregation (CD=10), rows stored with ld=12 (24B, 8B-aligned).
template <int CD>
__global__ void agg_code(
    const unsigned short* __restrict__ h,    // ld 12
    const int* __restrict__ row_start, const int2* __restrict__ csr_ent,
    const float* __restrict__ dinv,
    const float* __restrict__ bias,          // nullable
    float* __restrict__ Of,                  // nullable, ld CD (NT)
    unsigned short* __restrict__ Ob,         // nullable, ld ldo (zero-padded)
    int ldo, int N) {
  const int i = blockIdx.x * blockDim.x + threadIdx.x;
  if (i >= N) return;
  float acc[CD];
  float sn = dinv[i]; sn *= sn;
  {
    const unsigned short* hi = h + (size_t)i * 12;
    uint2 d0 = *(const uint2*)hi;
    uint2 d1 = *(const uint2*)(hi + 4);
    unsigned int d2 = *(const unsigned int*)(hi + 8);
    float t[10];
    up2(d0.x, t[0], t[1]); up2(d0.y, t[2], t[3]);
    up2(d1.x, t[4], t[5]); up2(d1.y, t[6], t[7]);
    up2(d2,   t[8], t[9]);
    #pragma unroll
    for (int f = 0; f < CD; ++f) acc[f] = t[f] * sn + (bias ? bias[f] : 0.f);
  }
  const int s1 = row_start[i + 1];
  for (int s = row_start[i]; s < s1; ++s) {
    long long p = __builtin_nontemporal_load((const long long*)(csr_ent + s));
    const unsigned short* hsr = h + (size_t)(int)p * 12;
    float wgt = i2f((int)(p >> 32));
    uint2 d0 = *(const uint2*)hsr;
    uint2 d1 = *(const uint2*)(hsr + 4);
    unsigned int d2 = *(const unsigned int*)(hsr + 8);
    float t[10];
    up2(d0.x, t[0], t[1]); up2(d0.y, t[2], t[3]);
    up2(d1.x, t[4], t[5]); up2(d1.y, t[6], t[7]);
    up2(d2,   t[8], t[9]);
    #pragma unroll
    for (int f = 0; f < CD; ++f) acc[f] = fmaf(t[f], wgt, acc[f]);
  }
  if (Of) {
    #pragma unroll
    for (int f = 0; f < CD; ++f)
      __builtin_nontemporal_store(acc[f], &Of[(size_t)i * CD + f]);
  }
  if (Ob) {
    if (ldo == 64) {
      unsigned short tmp[64];
      #pragma unroll
      for (int f = 0; f < CD; ++f) tmp[f] = f2b(acc[f]);
      #pragma unroll
      for (int f = CD; f < 64; ++f) tmp[f] = 0;
      unsigned short* op = Ob + (size_t)i * 64;
      #pragma unroll
      for (int c = 0; c < 8; ++c) *(short8*)(op + c * 8) = *(short8*)(tmp + c * 8);
    } else {
      #pragma unroll
      for (int f = 0; f < CD; ++f) Ob[(size_t)i * ldo + f] = f2b(acc[f]);
      for (int f = CD; f < ldo; ++f) Ob[(size_t)i * ldo + f] = 0;
    }
  }
}

// ---------------------------------------------------------------- driver

extern "C" void kernel_launch(void* const* d_in, const int* in_sizes, int n_in,
                              void* d_out, int out_size, void* d_ws, size_t ws_size,
                              hipStream_t stream) {
  const float* x   = (const float*)d_in[0];
  const int*   src = (const int*)d_in[1];
  const int*   dst = (const int*)d_in[2];
  const float* Wp[8];
  const float* bp[8];
  for (int i = 0; i < 8; ++i) {
    Wp[i] = (const float*)d_in[3 + 2 * i];
    bp[i] = (const float*)d_in[4 + 2 * i];
  }

  const int H = in_sizes[4];
  const int F = in_sizes[3] / H;
  const int N = in_sizes[0] / F;
  const int E = in_sizes[1];
  const int C = in_sizes[10];   // = 10

  const int Fp = (F + 63) & ~63;           // 512
  const int Cp = 64;                       // zagg ld (K padded to BK)
  const int dims[8][2] = { {F,H},{H,H},{H,H},{H,C},{C,H},{H,H},{H,H},{H,F} };

  // ---- workspace layout (256B aligned)
  char* ws = (char*)d_ws;
  size_t off = 0;
  auto alloc = [&](size_t bytes) {
    void* p = ws + off;
    off += (bytes + 255) & ~(size_t)255;
    return p;
  };
  int*   deg       = (int*)alloc((size_t)N * 4);
  int*   row_start = (int*)alloc((size_t)(N + 1) * 4);
  int*   cursor    = (int*)alloc((size_t)N * 4);
  float* dinv      = (float*)alloc((size_t)N * 4);
  int*   part      = (int*)alloc(1024 * 4);
  int2*  csr_ent   = (int2*)alloc((size_t)E * 8);
  unsigned short* xb = (unsigned short*)alloc((size_t)N * Fp * 2);
  WtPack wp;
  for (int i = 0; i < 8; ++i) {
    wp.W[i] = Wp[i];
    wp.K[i] = dims[i][0];
    wp.Nd[i] = dims[i][1];
    wp.Kp[i] = (dims[i][0] + 63) & ~63;
    wp.Ndp[i] = (dims[i][1] + 127) & ~127;
    wp.Wt[i] = (unsigned short*)alloc((size_t)wp.Ndp[i] * wp.Kp[i] * 2);
  }
  unsigned short* hb   = (unsigned short*)alloc((size_t)N * H * 2);
  unsigned short* actP = (unsigned short*)alloc((size_t)N * H * 2);
  unsigned short* actQ = (unsigned short*)alloc((size_t)N * H * 2);
  unsigned short* zpre = (unsigned short*)alloc((size_t)N * 12 * 2);
  unsigned short* zenb = (unsigned short*)alloc((size_t)N * 12 * 2);
  unsigned short* zagg = (unsigned short*)alloc((size_t)N * Cp * 2);
  (void)ws_size;

  // ---- d_out: x_de[N,F] | enc_h1[N,H] | enc_h2[N,H] | enc_h3[N,H] | z_en[N,C]
  float* out_f  = (float*)d_out;
  float* o_xde  = out_f;
  float* o_enc1 = out_f + (size_t)N * F;
  float* o_enc2 = o_enc1 + (size_t)N * H;
  float* o_enc3 = o_enc2 + (size_t)N * H;
  float* o_zen  = o_enc3 + (size_t)N * H;

  const int T = 256;
  const int nb = (N + 255) / 256;
  // ---- graph preprocessing
  k_zero_int<<<(N + T - 1) / T, T, 0, stream>>>(deg, N);
  k_deg<<<(E + T - 1) / T, T, 0, stream>>>(dst, deg, E);
  k_scan1<<<nb, 256, 0, stream>>>(deg, part, N);
  k_scan2<<<1, 1024, 0, stream>>>(part, nb);
  k_scan3<<<nb, 256, 0, stream>>>(deg, part, row_start, cursor, dinv, N);
  k_fill_csr<<<(E + T - 1) / T, T, 0, stream>>>(src, dst, dinv, cursor, csr_ent, E);
  // ---- conversions
  {
    int nth = N * (Fp >> 3);
    k_cvt_pad<<<(nth + T - 1) / T, T, 0, stream>>>(x, xb, N, F, Fp);
    int maxElems = 0;
    for (int i = 0; i < 8; ++i) {
      int e = wp.Kp[i] * wp.Ndp[i];
      if (e > maxElems) maxElems = e;
    }
    dim3 g((maxElems + T - 1) / T, 8);
    k_wt_all<<<g, T, 0, stream>>>(wp);
  }

  auto gemm = [&](const unsigned short* A, int lda, int widx, const float* bias,
                  float* Cf, int ldcf, unsigned short* Cb, int ldcb,
                  int Nd, int relu) {
    dim3 grid((N + 127) / 128, (Nd + 127) / 128);
    gemm_bf16<<<grid, 256, 0, stream>>>(A, wp.Wt[widx], bias, Cf, ldcf, Cb, ldcb,
                                        N, wp.Kp[widx], Nd, lda, relu);
  };
  auto agg256 = [&](const unsigned short* h, const float* bias, float* Of,
                    unsigned short* Ob, int relu) {
    agg_wave<<<(N + 3) / 4, 256, 0, stream>>>(h, row_start, csr_ent,
                                              dinv, bias, Of, Ob, N, relu);
  };

  // enc1: h = xb @ W0 ; enc_h1 = relu(agg(h)+b0)
  gemm(xb, Fp, 0, nullptr, nullptr, 0, hb, H, H, 0);
  agg256(hb, bp[0], o_enc1, actP, 1);
  // enc2
  gemm(actP, H, 1, nullptr, nullptr, 0, hb, H, H, 0);
  agg256(hb, bp[1], o_enc2, actQ, 1);
  // enc3
  gemm(actQ, H, 2, nullptr, nullptr, 0, hb, H, H, 0);
  agg256(hb, bp[2], o_enc3, actP, 1);
  // zen: zpre = enc_h3 @ W3 (ld 12) ; z_en = agg(zpre) + b3
  gemm(actP, H, 3, nullptr, nullptr, 0, zpre, 12, C, 0);
  agg_code<10><<<(N + T - 1) / T, T, 0, stream>>>(
      zpre, row_start, csr_ent, dinv, bp[3], o_zen, zenb, 12, N);
  // dec1 (linearity): zagg = agg_nobias(z_en) ; d1 = relu(zagg @ W4 + b4)
  agg_code<10><<<(N + T - 1) / T, T, 0, stream>>>(
      zenb, row_start, csr_ent, dinv, nullptr, nullptr, zagg, Cp, N);
  gemm(zagg, Cp, 4, bp[4], nullptr, 0, actQ, H, H, 1);
  // dec2
  gemm(actQ, H, 5, nullptr, nullptr, 0, hb, H, H, 0);
  agg256(hb, bp[5], nullptr, actP, 1);
  // dec3
  gemm(actP, H, 6, nullptr, nullptr, 0, hb, H, H, 0);
  agg256(hb, bp[6], nullptr, actQ, 1);
  // xde (linearity): dagg = agg_nobias(d3) ; x_de = dagg @ W7 + b7 (fp32)
  agg256(actQ, nullptr, nullptr, actP, 0);
  gemm(actP, H, 7, bp[7], o_xde, F, nullptr, 0, F, 0);
}

// Round 10
// 719.810 us; speedup vs baseline: 1.3772x; 1.3772x over previous
//
#include <hip/hip_runtime.h>

// GCN autoencoder on MI355X (gfx950).
// bf16-MFMA GEMM (BK=32, global_load_lds, counted vmcnt, LDS-staged epilogue)
// + deep-unrolled gather agg (at fabric roofline).
// N=50000, E=800000, F=500, H=256, C=10 (derived at runtime).

typedef __attribute__((ext_vector_type(8))) short short8;           // 8 bf16
typedef __attribute__((ext_vector_type(4))) float f32x4;            // MFMA acc

// ---------------------------------------------------------------- helpers

__device__ __forceinline__ float b2f(unsigned short u) {
  union { unsigned int i; float f; } v; v.i = ((unsigned int)u) << 16; return v.f;
}
__device__ __forceinline__ unsigned short f2b(float f) {  // RNE
  union { float f; unsigned int i; } v; v.f = f;
  unsigned int r = v.i + 0x7FFFu + ((v.i >> 16) & 1u);
  return (unsigned short)(r >> 16);
}
__device__ __forceinline__ void up2(unsigned int u, float& a, float& b) {
  union { unsigned int i; float f; } x, y;
  x.i = u << 16; y.i = u & 0xffff0000u;
  a = x.f; b = y.f;
}
__device__ __forceinline__ float i2f(int i) {
  union { int i; float f; } v; v.i = i; return v.f;
}

// async global->LDS, 16B per lane; dest = lds_base(wave-uniform) + lane*16
__device__ __forceinline__ void gload16(const void* g, void* l) {
  __builtin_amdgcn_global_load_lds(
      (const __attribute__((address_space(1))) unsigned int*)g,
      (__attribute__((address_space(3))) unsigned int*)l, 16, 0, 0);
}

// ---------------------------------------------------------------- preproc

__global__ void k_zero_int(int* __restrict__ p, int n) {
  int i = blockIdx.x * blockDim.x + threadIdx.x;
  if (i < n) p[i] = 0;
}

__global__ void k_deg(const int* __restrict__ dst, int* __restrict__ deg, int E) {
  int i = blockIdx.x * blockDim.x + threadIdx.x;
  if (i < E) atomicAdd(&deg[dst[i]], 1);
}

// 3-pass parallel scan (n up to 256*1024)
__global__ void k_scan1(const int* __restrict__ deg, int* __restrict__ part, int n) {
  __shared__ int sh[256];
  int i = blockIdx.x * 256 + threadIdx.x;
  sh[threadIdx.x] = (i < n) ? deg[i] : 0;
  __syncthreads();
  for (int o = 128; o > 0; o >>= 1) {
    if (threadIdx.x < o) sh[threadIdx.x] += sh[threadIdx.x + o];
    __syncthreads();
  }
  if (threadIdx.x == 0) part[blockIdx.x] = sh[0];
}

__global__ __launch_bounds__(1024) void k_scan2(int* __restrict__ part, int nb) {
  __shared__ int sh[1024];
  int t = threadIdx.x;
  int v = (t < nb) ? part[t] : 0;
  sh[t] = v;
  __syncthreads();
  for (int off = 1; off < 1024; off <<= 1) {
    int u = (t >= off) ? sh[t - off] : 0;
    __syncthreads();
    sh[t] += u;
    __syncthreads();
  }
  if (t < nb) part[t] = sh[t] - v;  // exclusive
}

__global__ void k_scan3(const int* __restrict__ deg, const int* __restrict__ part,
                        int* __restrict__ row_start, int* __restrict__ cursor,
                        float* __restrict__ dinv, int n) {
  __shared__ int sh[256];
  int t = threadIdx.x;
  int i = blockIdx.x * 256 + t;
  int v = (i < n) ? deg[i] : 0;
  sh[t] = v;
  __syncthreads();
  for (int off = 1; off < 256; off <<= 1) {
    int u = (t >= off) ? sh[t - off] : 0;
    __syncthreads();
    sh[t] += u;
    __syncthreads();
  }
  if (i < n) {
    int excl = part[blockIdx.x] + sh[t] - v;
    row_start[i] = excl;
    cursor[i] = excl;
    dinv[i] = rsqrtf((float)v + 1.0f);
    if (i == n - 1) row_start[n] = excl + v;
  }
}

// fused CSR entries: .x = src index, .y = float bits of norm
__global__ void k_fill_csr(const int* __restrict__ src, const int* __restrict__ dst,
                           const float* __restrict__ dinv, int* __restrict__ cursor,
                           int2* __restrict__ csr_ent, int E) {
  int e = blockIdx.x * blockDim.x + threadIdx.x;
  if (e < E) {
    int d = dst[e];
    int s = src[e];
    int pos = atomicAdd(&cursor[d], 1);
    float nrm = dinv[s] * dinv[d];
    csr_ent[pos] = make_int2(s, __float_as_int(nrm));
  }
}

// x[N][F] fp32 -> xb[N][Fp] bf16, zero-padded cols
__global__ void k_cvt_pad(const float* __restrict__ in, unsigned short* __restrict__ out,
                          int N, int F, int Fp) {
  int idx = blockIdx.x * blockDim.x + threadIdx.x;
  int perRow = Fp >> 3;
  int row = idx / perRow;
  int c = (idx - row * perRow) << 3;
  if (row >= N) return;
  unsigned short o[8];
  if (c + 8 <= F) {
    const float* p = in + (size_t)row * F + c;
    #pragma unroll
    for (int e = 0; e < 8; ++e) o[e] = f2b(p[e]);
  } else {
    #pragma unroll
    for (int e = 0; e < 8; ++e) {
      int cc = c + e;
      o[e] = (cc < F) ? f2b(in[(size_t)row * F + cc]) : (unsigned short)0;
    }
  }
  *(short8*)(out + (size_t)row * Fp + c) = *(short8*)o;
}

// all 8 weights: W[K][Nd] fp32 -> Wt[Ndp][Kp] bf16 (transposed, zero-padded)
struct WtPack {
  const float* W[8];
  unsigned short* Wt[8];
  int K[8], Nd[8], Kp[8], Ndp[8];
};

__global__ void k_wt_all(WtPack p) {
  int l = blockIdx.y;
  int idx = blockIdx.x * blockDim.x + threadIdx.x;
  int Kp = p.Kp[l], Ndp = p.Ndp[l];
  if (idx >= Kp * Ndp) return;
  int n = idx / Kp, k = idx - n * Kp;
  unsigned short v = 0;
  if (n < p.Nd[l] && k < p.K[l]) v = f2b(p.W[l][(size_t)k * p.Nd[l] + n]);
  p.Wt[l][idx] = v;
}

// ---------------------------------------------------------------- GEMM
// C[M,Nd] = A[M,Kp] @ Bt^T, A bf16 [M][lda], Bt bf16 [Ndp][Kp], padded.
// 128x128 tile, 4 waves (2x2), BK=32, 4x4 frags of mfma_f32_16x16x32_bf16.
// global_load_lds staging, 2-deep, counted vmcnt across raw barriers.
// Slot-swizzle (slot ^= (row>>1)&3) at global source AND ds_read (R7-proven).
// Epilogue: stage C tile through the (now idle) 32KB smem, copy out with
// row-contiguous vector stores (16 lanes = one bf16 row / 32 lanes = one f32 row).
// smem layout (ushort units): As0 @0, As1 @4096, Bs0 @8192, Bs1 @12288.

__global__ __launch_bounds__(256) void gemm_bf16(
    const unsigned short* __restrict__ A,
    const unsigned short* __restrict__ Bt,
    const float* __restrict__ bias,     // nullable, [Nd]
    float* __restrict__ Cf, int ldcf,   // nullable
    unsigned short* __restrict__ Cb, int ldcb,  // nullable
    int M, int Kp, int Nd, int lda, int relu) {
  __shared__ __attribute__((aligned(16))) unsigned short smem[16384];  // 32KB

  const int bm = blockIdx.x * 128;
  const int bn = blockIdx.y * 128;
  const int tid = threadIdx.x;
  const int wid = tid >> 6;
  const int lane = tid & 63;

  const unsigned short* srcA[2];
  const unsigned short* srcB[2];
  #pragma unroll
  for (int j = 0; j < 2; ++j) {
    int chunk = wid * 2 + j;
    int r_st = chunk * 16 + (lane >> 2);
    int slot = lane & 3;
    int sw = slot ^ ((r_st >> 1) & 3);
    int gm = bm + r_st; if (gm > M - 1) gm = M - 1;   // clamp: dup rows unused
    srcA[j] = A + (size_t)gm * lda + sw * 8;
    int gn = bn + r_st;                                // < Ndp (padded)
    srcB[j] = Bt + (size_t)gn * Kp + sw * 8;
  }

  const int wr = wid >> 1, wc = wid & 1;
  const int lrow = lane & 15;
  const int kgrp = lane >> 4;
  const int rA = wr * 64 + lrow;
  const int rB = wc * 64 + lrow;
  const int aoff = rA * 32 + (kgrp ^ ((rA >> 1) & 3)) * 8;
  const int boff = rB * 32 + (kgrp ^ ((rB >> 1) & 3)) * 8;

  f32x4 acc[4][4];
  #pragma unroll
  for (int i = 0; i < 4; ++i)
    #pragma unroll
    for (int j = 0; j < 4; ++j) acc[i][j] = (f32x4){0.f, 0.f, 0.f, 0.f};

  auto stage = [&](int buf, int k0) {
    unsigned short* As = smem + buf * 4096;
    unsigned short* Bs = smem + 8192 + buf * 4096;
    #pragma unroll
    for (int j = 0; j < 2; ++j) {
      int chunk = wid * 2 + j;
      gload16(srcA[j] + k0, As + chunk * 512);
      gload16(srcB[j] + k0, Bs + chunk * 512);
    }
  };

  const int nt = Kp >> 5;
  stage(0, 0);
  if (nt > 1) stage(1, 32);
  int cur = 0;
  for (int t = 0; t < nt; ++t) {
    if (t + 1 < nt) asm volatile("s_waitcnt vmcnt(4)\n\ts_barrier" ::: "memory");
    else            asm volatile("s_waitcnt vmcnt(0)\n\ts_barrier" ::: "memory");

    const unsigned short* pA = smem + cur * 4096 + aoff;
    const unsigned short* pB = smem + 8192 + cur * 4096 + boff;
    short8 a[4], b[4];
    #pragma unroll
    for (int mi = 0; mi < 4; ++mi) a[mi] = *(const short8*)(pA + mi * 512);
    #pragma unroll
    for (int nj = 0; nj < 4; ++nj) b[nj] = *(const short8*)(pB + nj * 512);

    asm volatile("s_waitcnt lgkmcnt(0)\n\ts_barrier" ::: "memory");
    __builtin_amdgcn_sched_barrier(0);

    if (t + 2 < nt) stage(cur, (t + 2) * 32);

    #pragma unroll
    for (int mi = 0; mi < 4; ++mi)
      #pragma unroll
      for (int nj = 0; nj < 4; ++nj)
        acc[mi][nj] = __builtin_amdgcn_mfma_f32_16x16x32_bf16(a[mi], b[nj], acc[mi][nj], 0, 0, 0);
    cur ^= 1;
  }
  // After the loop: no outstanding DMA (vmcnt(0) waited at last iter), and the
  // last lgkmcnt(0)+barrier retired every wave's ds_reads -> smem reusable.

  float bv[4];
  #pragma unroll
  for (int nj = 0; nj < 4; ++nj) {
    int gn = bn + wc * 64 + nj * 16 + lrow;
    bv[nj] = (bias && gn < Nd) ? bias[gn] : 0.f;
  }

  if (Cb && Nd >= 128) {
    // bf16 C tile [128][128] = 32KB, staged in smem, coalesced copy-out.
    unsigned short* Lb = smem;
    #pragma unroll
    for (int mi = 0; mi < 4; ++mi)
      #pragma unroll
      for (int rr = 0; rr < 4; ++rr) {
        int row = wr * 64 + mi * 16 + 4 * kgrp + rr;
        #pragma unroll
        for (int nj = 0; nj < 4; ++nj) {
          float v = acc[mi][nj][rr] + bv[nj];
          if (relu) v = fmaxf(v, 0.f);
          Lb[row * 128 + wc * 64 + nj * 16 + lrow] = f2b(v);
        }
      }
    __syncthreads();
    #pragma unroll
    for (int c = 0; c < 8; ++c) {
      int g = c * 256 + tid;
      int r = g >> 4, cc = g & 15;        // 16 lanes = one full 256B row
      int gm = bm + r;
      if (gm < M)
        *(short8*)(Cb + (size_t)gm * ldcb + bn + cc * 8) =
            *(const short8*)(Lb + r * 128 + cc * 8);
    }
  } else if (Cf && Nd >= 128) {
    // fp32 C tile staged in two 64-row passes ([64][128] f32 = 32KB).
    float* Lf = (float*)smem;
    #pragma unroll
    for (int p = 0; p < 2; ++p) {
      if (wr == p) {
        #pragma unroll
        for (int mi = 0; mi < 4; ++mi)
          #pragma unroll
          for (int rr = 0; rr < 4; ++rr) {
            int row = mi * 16 + 4 * kgrp + rr;   // 0..63 within half
            #pragma unroll
            for (int nj = 0; nj < 4; ++nj) {
              float v = acc[mi][nj][rr] + bv[nj];
              if (relu) v = fmaxf(v, 0.f);
              Lf[row * 128 + wc * 64 + nj * 16 + lrow] = v;
            }
          }
      }
      __syncthreads();
      #pragma unroll
      for (int c = 0; c < 8; ++c) {
        int g = c * 256 + tid;
        int r = g >> 5, cc = g & 31;      // 32 lanes = one full 512B row
        int gm = bm + p * 64 + r;
        int col = bn + cc * 4;
        if (gm < M) {
          const float* sp = Lf + r * 128 + cc * 4;
          if (col + 4 <= Nd) {
            __builtin_nontemporal_store(*(const f32x4*)sp,
                                        (f32x4*)(Cf + (size_t)gm * ldcf + col));
          } else {
            #pragma unroll
            for (int e = 0; e < 4; ++e)
              if (col + e < Nd) Cf[(size_t)gm * ldcf + col + e] = sp[e];
          }
        }
      }
      __syncthreads();
    }
  } else {
    // narrow-Nd scalar path (zen, Nd=10)
    const int orow = bm + wr * 64;
    const int ocol = bn + wc * 64;
    #pragma unroll
    for (int mi = 0; mi < 4; ++mi) {
      #pragma unroll
      for (int rr = 0; rr < 4; ++rr) {
        int gm = orow + mi * 16 + 4 * kgrp + rr;
        if (gm >= M) continue;
        #pragma unroll
        for (int nj = 0; nj < 4; ++nj) {
          int gn = ocol + nj * 16 + lrow;
          if (gn >= Nd) continue;
          float v = acc[mi][nj][rr] + bv[nj];
          if (relu) v = fmaxf(v, 0.f);
          if (Cf) Cf[(size_t)gm * ldcf + gn] = v;
          if (Cb) Cb[(size_t)gm * ldcb + gn] = f2b(v);
        }
      }
    }
  }
}

// ---------------------------------------------------------------- aggregation
// Wave per node; two 32-lane halves, each gathers its own edges at 16B/lane.
// 16 edges per main trip (8 per half). Fused int2 CSR entries, NT-loaded.
// Cross-half combine via shfl_xor(32). half0 stores bf16 mirror; half1 fp32 NT.

__global__ __launch_bounds__(256) void agg_wave(
    const unsigned short* __restrict__ h,
    const int* __restrict__ row_start, const int2* __restrict__ csr_ent,
    const float* __restrict__ dinv,
    const float* __restrict__ bias,      // nullable
    float* __restrict__ Of,              // nullable
    unsigned short* __restrict__ Ob,     // nullable
    int N, int relu) {
  const int w = threadIdx.x >> 6;
  const int lane = threadIdx.x & 63;
  const int i = blockIdx.x * 4 + w;
  if (i >= N) return;
  const int half = lane >> 5;
  const int hl = lane & 31;
  const int f0 = hl * 8;

  float acc[8];
  if (half == 0) {
    float sn = dinv[i]; sn *= sn;
    short8 hv = *(const short8*)(h + ((size_t)i << 8) + f0);
    #pragma unroll
    for (int j = 0; j < 8; ++j) acc[j] = b2f(((const unsigned short*)&hv)[j]) * sn;
  } else if (bias) {
    #pragma unroll
    for (int j = 0; j < 8; ++j) acc[j] = bias[f0 + j];
  } else {
    #pragma unroll
    for (int j = 0; j < 8; ++j) acc[j] = 0.f;
  }

  int s = row_start[i];
  const int s1 = row_start[i + 1];

  // main: 16 edges per trip (8 per half) -> 8 gathers in flight per lane
  for (; s + 16 <= s1; s += 16) {
    long long pe[8];
    #pragma unroll
    for (int k = 0; k < 8; ++k)
      pe[k] = __builtin_nontemporal_load((const long long*)(csr_ent + s + 2 * k + half));
    short8 ve[8];
    #pragma unroll
    for (int k = 0; k < 8; ++k)
      ve[k] = *(const short8*)(h + ((size_t)(int)pe[k] << 8) + f0);
    #pragma unroll
    for (int k = 0; k < 8; ++k) {
      float wt = i2f((int)(pe[k] >> 32));
      #pragma unroll
      for (int j = 0; j < 8; ++j)
        acc[j] = fmaf(b2f(((const unsigned short*)&ve[k])[j]), wt, acc[j]);
    }
  }
  // 8 edges (4 per half)
  for (; s + 8 <= s1; s += 8) {
    long long pe[4];
    #pragma unroll
    for (int k = 0; k < 4; ++k)
      pe[k] = __builtin_nontemporal_load((const long long*)(csr_ent + s + 2 * k + half));
    short8 ve[4];
    #pragma unroll
    for (int k = 0; k < 4; ++k)
      ve[k] = *(const short8*)(h + ((size_t)(int)pe[k] << 8) + f0);
    #pragma unroll
    for (int k = 0; k < 4; ++k) {
      float wt = i2f((int)(pe[k] >> 32));
      #pragma unroll
      for (int j = 0; j < 8; ++j)
        acc[j] = fmaf(b2f(((const unsigned short*)&ve[k])[j]), wt, acc[j]);
    }
  }
  // 4 edges (2 per half)
  for (; s + 4 <= s1; s += 4) {
    long long p0 = __builtin_nontemporal_load((const long long*)(csr_ent + s + half));
    long long p1 = __builtin_nontemporal_load((const long long*)(csr_ent + s + 2 + half));
    short8 v0 = *(const short8*)(h + ((size_t)(int)p0 << 8) + f0);
    short8 v1 = *(const short8*)(h + ((size_t)(int)p1 << 8) + f0);
    float w0 = i2f((int)(p0 >> 32)), w1 = i2f((int)(p1 >> 32));
    #pragma unroll
    for (int j = 0; j < 8; ++j)
      acc[j] = fmaf(b2f(((const unsigned short*)&v0)[j]), w0, acc[j]);
    #pragma unroll
    for (int j = 0; j < 8; ++j)
      acc[j] = fmaf(b2f(((const unsigned short*)&v1)[j]), w1, acc[j]);
  }
  // predicated pairs
  for (; s < s1; s += 2) {
    int e = s + half;
    bool valid = e < s1;
    long long p0 = valid
        ? __builtin_nontemporal_load((const long long*)(csr_ent + e)) : 0ll;
    short8 vv = *(const short8*)(h + ((size_t)(int)p0 << 8) + f0);
    float wt = i2f((int)(p0 >> 32));
    #pragma unroll
    for (int j = 0; j < 8; ++j)
      acc[j] = fmaf(b2f(((const unsigned short*)&vv)[j]), wt, acc[j]);
  }

  #pragma unroll
  for (int j = 0; j < 8; ++j) acc[j] += __shfl_xor(acc[j], 32, 64);
  if (relu) {
    #pragma unroll
    for (int j = 0; j < 8; ++j) acc[j] = fmaxf(acc[j], 0.f);
  }

  size_t o = ((size_t)i << 8) + f0;
  if (half == 0) {
    if (Ob) {
      unsigned short ob[8];
      #pragma unroll
      for (int j = 0; j < 8; ++j) ob[j] = f2b(acc[j]);
      *(short8*)(Ob + o) = *(short8*)ob;
    }
  } else if (Of) {
    f32x4 lo = {acc[0], acc[1], acc[2], acc[3]};
    f32x4 hi = {acc[4], acc[5], acc[6], acc[7]};
    __builtin_nontemporal_store(lo, (f32x4*)(Of + o));
    __builtin_nontemporal_store(hi, (f32x4*)(Of + o + 4));
  }
}

// Code-path aggregation (CD=10), rows stored with ld=12 (24B, 8B-aligned).
template <int CD>
__global__ void agg_code(
    const unsigned short* __restrict__ h,    // ld 12
    const int* __restrict__ row_start, const int2* __restrict__ csr_ent,
    const float* __restrict__ dinv,
    const float* __restrict__ bias,          // nullable
    float* __restrict__ Of,                  // nullable, ld CD (NT)
    unsigned short* __restrict__ Ob,         // nullable, ld ldo (zero-padded)
    int ldo, int N) {
  const int i = blockIdx.x * blockDim.x + threadIdx.x;
  if (i >= N) return;
  float acc[CD];
  float sn = dinv[i]; sn *= sn;
  {
    const unsigned short* hi = h + (size_t)i * 12;
    uint2 d0 = *(const uint2*)hi;
    uint2 d1 = *(const uint2*)(hi + 4);
    unsigned int d2 = *(const unsigned int*)(hi + 8);
    float t[10];
    up2(d0.x, t[0], t[1]); up2(d0.y, t[2], t[3]);
    up2(d1.x, t[4], t[5]); up2(d1.y, t[6], t[7]);
    up2(d2,   t[8], t[9]);
    #pragma unroll
    for (int f = 0; f < CD; ++f) acc[f] = t[f] * sn + (bias ? bias[f] : 0.f);
  }
  const int s1 = row_start[i + 1];
  for (int s = row_start[i]; s < s1; ++s) {
    long long p = __builtin_nontemporal_load((const long long*)(csr_ent + s));
    const unsigned short* hsr = h + (size_t)(int)p * 12;
    float wgt = i2f((int)(p >> 32));
    uint2 d0 = *(const uint2*)hsr;
    uint2 d1 = *(const uint2*)(hsr + 4);
    unsigned int d2 = *(const unsigned int*)(hsr + 8);
    float t[10];
    up2(d0.x, t[0], t[1]); up2(d0.y, t[2], t[3]);
    up2(d1.x, t[4], t[5]); up2(d1.y, t[6], t[7]);
    up2(d2,   t[8], t[9]);
    #pragma unroll
    for (int f = 0; f < CD; ++f) acc[f] = fmaf(t[f], wgt, acc[f]);
  }
  if (Of) {
    #pragma unroll
    for (int f = 0; f < CD; ++f)
      __builtin_nontemporal_store(acc[f], &Of[(size_t)i * CD + f]);
  }
  if (Ob) {
    #pragma unroll
    for (int f = 0; f < CD; ++f) Ob[(size_t)i * ldo + f] = f2b(acc[f]);
    for (int f = CD; f < ldo; ++f) Ob[(size_t)i * ldo + f] = 0;
  }
}

// ---------------------------------------------------------------- driver

extern "C" void kernel_launch(void* const* d_in, const int* in_sizes, int n_in,
                              void* d_out, int out_size, void* d_ws, size_t ws_size,
                              hipStream_t stream) {
  const float* x   = (const float*)d_in[0];
  const int*   src = (const int*)d_in[1];
  const int*   dst = (const int*)d_in[2];
  const float* Wp[8];
  const float* bp[8];
  for (int i = 0; i < 8; ++i) {
    Wp[i] = (const float*)d_in[3 + 2 * i];
    bp[i] = (const float*)d_in[4 + 2 * i];
  }

  const int H = in_sizes[4];
  const int F = in_sizes[3] / H;
  const int N = in_sizes[0] / F;
  const int E = in_sizes[1];
  const int C = in_sizes[10];   // = 10

  const int Fp = (F + 31) & ~31;           // 512
  const int Cp = (C + 31) & ~31;           // 32
  const int dims[8][2] = { {F,H},{H,H},{H,H},{H,C},{C,H},{H,H},{H,H},{H,F} };

  // ---- workspace layout (256B aligned)
  char* ws = (char*)d_ws;
  size_t off = 0;
  auto alloc = [&](size_t bytes) {
    void* p = ws + off;
    off += (bytes + 255) & ~(size_t)255;
    return p;
  };
  int*   deg       = (int*)alloc((size_t)N * 4);
  int*   row_start = (int*)alloc((size_t)(N + 1) * 4);
  int*   cursor    = (int*)alloc((size_t)N * 4);
  float* dinv      = (float*)alloc((size_t)N * 4);
  int*   part      = (int*)alloc(1024 * 4);
  int2*  csr_ent   = (int2*)alloc((size_t)E * 8);
  unsigned short* xb = (unsigned short*)alloc((size_t)N * Fp * 2);
  WtPack wp;
  for (int i = 0; i < 8; ++i) {
    wp.W[i] = Wp[i];
    wp.K[i] = dims[i][0];
    wp.Nd[i] = dims[i][1];
    wp.Kp[i] = (dims[i][0] + 31) & ~31;
    wp.Ndp[i] = (dims[i][1] + 127) & ~127;
    wp.Wt[i] = (unsigned short*)alloc((size_t)wp.Ndp[i] * wp.Kp[i] * 2);
  }
  unsigned short* hb   = (unsigned short*)alloc((size_t)N * H * 2);
  unsigned short* actP = (unsigned short*)alloc((size_t)N * H * 2);
  unsigned short* actQ = (unsigned short*)alloc((size_t)N * H * 2);
  unsigned short* zpre = (unsigned short*)alloc((size_t)N * 12 * 2);
  unsigned short* zenb = (unsigned short*)alloc((size_t)N * 12 * 2);
  unsigned short* zagg = (unsigned short*)alloc((size_t)N * Cp * 2);
  (void)ws_size;

  // ---- d_out: x_de[N,F] | enc_h1[N,H] | enc_h2[N,H] | enc_h3[N,H] | z_en[N,C]
  float* out_f  = (float*)d_out;
  float* o_xde  = out_f;
  float* o_enc1 = out_f + (size_t)N * F;
  float* o_enc2 = o_enc1 + (size_t)N * H;
  float* o_enc3 = o_enc2 + (size_t)N * H;
  float* o_zen  = o_enc3 + (size_t)N * H;

  const int T = 256;
  const int nb = (N + 255) / 256;
  // ---- graph preprocessing
  k_zero_int<<<(N + T - 1) / T, T, 0, stream>>>(deg, N);
  k_deg<<<(E + T - 1) / T, T, 0, stream>>>(dst, deg, E);
  k_scan1<<<nb, 256, 0, stream>>>(deg, part, N);
  k_scan2<<<1, 1024, 0, stream>>>(part, nb);
  k_scan3<<<nb, 256, 0, stream>>>(deg, part, row_start, cursor, dinv, N);
  k_fill_csr<<<(E + T - 1) / T, T, 0, stream>>>(src, dst, dinv, cursor, csr_ent, E);
  // ---- conversions
  {
    int nth = N * (Fp >> 3);
    k_cvt_pad<<<(nth + T - 1) / T, T, 0, stream>>>(x, xb, N, F, Fp);
    int maxElems = 0;
    for (int i = 0; i < 8; ++i) {
      int e = wp.Kp[i] * wp.Ndp[i];
      if (e > maxElems) maxElems = e;
    }
    dim3 g((maxElems + T - 1) / T, 8);
    k_wt_all<<<g, T, 0, stream>>>(wp);
  }

  auto gemm = [&](const unsigned short* A, int lda, int widx, const float* bias,
                  float* Cf, int ldcf, unsigned short* Cb, int ldcb,
                  int Nd, int relu) {
    dim3 grid((N + 127) / 128, (Nd + 127) / 128);
    gemm_bf16<<<grid, 256, 0, stream>>>(A, wp.Wt[widx], bias, Cf, ldcf, Cb, ldcb,
                                        N, wp.Kp[widx], Nd, lda, relu);
  };
  auto agg256 = [&](const unsigned short* h, const float* bias, float* Of,
                    unsigned short* Ob, int relu) {
    agg_wave<<<(N + 3) / 4, 256, 0, stream>>>(h, row_start, csr_ent,
                                              dinv, bias, Of, Ob, N, relu);
  };

  // enc1: h = xb @ W0 ; enc_h1 = relu(agg(h)+b0)
  gemm(xb, Fp, 0, nullptr, nullptr, 0, hb, H, H, 0);
  agg256(hb, bp[0], o_enc1, actP, 1);
  // enc2
  gemm(actP, H, 1, nullptr, nullptr, 0, hb, H, H, 0);
  agg256(hb, bp[1], o_enc2, actQ, 1);
  // enc3
  gemm(actQ, H, 2, nullptr, nullptr, 0, hb, H, H, 0);
  agg256(hb, bp[2], o_enc3, actP, 1);
  // zen: zpre = enc_h3 @ W3 (ld 12) ; z_en = agg(zpre) + b3
  gemm(actP, H, 3, nullptr, nullptr, 0, zpre, 12, C, 0);
  agg_code<10><<<(N + T - 1) / T, T, 0, stream>>>(
      zpre, row_start, csr_ent, dinv, bp[3], o_zen, zenb, 12, N);
  // dec1 (linearity): zagg = agg_nobias(z_en) ; d1 = relu(zagg @ W4 + b4)
  agg_code<10><<<(N + T - 1) / T, T, 0, stream>>>(
      zenb, row_start, csr_ent, dinv, nullptr, nullptr, zagg, Cp, N);
  gemm(zagg, Cp, 4, bp[4], nullptr, 0, actQ, H, H, 1);
  // dec2
  gemm(actQ, H, 5, nullptr, nullptr, 0, hb, H, H, 0);
  agg256(hb, bp[5], nullptr, actP, 1);
  // dec3
  gemm(actP, H, 6, nullptr, nullptr, 0, hb, H, H, 0);
  agg256(hb, bp[6], nullptr, actQ, 1);
  // xde (linearity): dagg = agg_nobias(d3) ; x_de = dagg @ W7 + b7 (fp32)
  agg256(actQ, nullptr, nullptr, actP, 0);
  gemm(actP, H, 7, bp[7], o_xde, F, nullptr, 0, F, 0);
}

// Round 11
// 706.829 us; speedup vs baseline: 1.4025x; 1.0184x over previous
//
#include <hip/hip_runtime.h>

// GCN autoencoder on MI355X (gfx950).
// bf16-MFMA GEMM (BK=32, global_load_lds, counted vmcnt, LDS-staged epilogue,
// XCD-paired 1-D grid swizzle) + deep-unrolled gather agg (fabric roofline).
// N=50000, E=800000, F=500, H=256, C=10 (derived at runtime).

typedef __attribute__((ext_vector_type(8))) short short8;           // 8 bf16
typedef __attribute__((ext_vector_type(4))) float f32x4;            // MFMA acc

// ---------------------------------------------------------------- helpers

__device__ __forceinline__ float b2f(unsigned short u) {
  union { unsigned int i; float f; } v; v.i = ((unsigned int)u) << 16; return v.f;
}
__device__ __forceinline__ unsigned short f2b(float f) {  // RNE
  union { float f; unsigned int i; } v; v.f = f;
  unsigned int r = v.i + 0x7FFFu + ((v.i >> 16) & 1u);
  return (unsigned short)(r >> 16);
}
__device__ __forceinline__ void up2(unsigned int u, float& a, float& b) {
  union { unsigned int i; float f; } x, y;
  x.i = u << 16; y.i = u & 0xffff0000u;
  a = x.f; b = y.f;
}
__device__ __forceinline__ float i2f(int i) {
  union { int i; float f; } v; v.i = i; return v.f;
}

// async global->LDS, 16B per lane; dest = lds_base(wave-uniform) + lane*16
__device__ __forceinline__ void gload16(const void* g, void* l) {
  __builtin_amdgcn_global_load_lds(
      (const __attribute__((address_space(1))) unsigned int*)g,
      (__attribute__((address_space(3))) unsigned int*)l, 16, 0, 0);
}

// ---------------------------------------------------------------- preproc

__global__ void k_zero_int(int* __restrict__ p, int n) {
  int i = blockIdx.x * blockDim.x + threadIdx.x;
  if (i < n) p[i] = 0;
}

__global__ void k_deg(const int* __restrict__ dst, int* __restrict__ deg, int E) {
  int i = blockIdx.x * blockDim.x + threadIdx.x;
  if (i < E) atomicAdd(&deg[dst[i]], 1);
}

// 3-pass parallel scan (n up to 256*1024)
__global__ void k_scan1(const int* __restrict__ deg, int* __restrict__ part, int n) {
  __shared__ int sh[256];
  int i = blockIdx.x * 256 + threadIdx.x;
  sh[threadIdx.x] = (i < n) ? deg[i] : 0;
  __syncthreads();
  for (int o = 128; o > 0; o >>= 1) {
    if (threadIdx.x < o) sh[threadIdx.x] += sh[threadIdx.x + o];
    __syncthreads();
  }
  if (threadIdx.x == 0) part[blockIdx.x] = sh[0];
}

__global__ __launch_bounds__(1024) void k_scan2(int* __restrict__ part, int nb) {
  __shared__ int sh[1024];
  int t = threadIdx.x;
  int v = (t < nb) ? part[t] : 0;
  sh[t] = v;
  __syncthreads();
  for (int off = 1; off < 1024; off <<= 1) {
    int u = (t >= off) ? sh[t - off] : 0;
    __syncthreads();
    sh[t] += u;
    __syncthreads();
  }
  if (t < nb) part[t] = sh[t] - v;  // exclusive
}

__global__ void k_scan3(const int* __restrict__ deg, const int* __restrict__ part,
                        int* __restrict__ row_start, int* __restrict__ cursor,
                        float* __restrict__ dinv, int n) {
  __shared__ int sh[256];
  int t = threadIdx.x;
  int i = blockIdx.x * 256 + t;
  int v = (i < n) ? deg[i] : 0;
  sh[t] = v;
  __syncthreads();
  for (int off = 1; off < 256; off <<= 1) {
    int u = (t >= off) ? sh[t - off] : 0;
    __syncthreads();
    sh[t] += u;
    __syncthreads();
  }
  if (i < n) {
    int excl = part[blockIdx.x] + sh[t] - v;
    row_start[i] = excl;
    cursor[i] = excl;
    dinv[i] = rsqrtf((float)v + 1.0f);
    if (i == n - 1) row_start[n] = excl + v;
  }
}

// fused CSR entries: .x = src index, .y = float bits of norm
__global__ void k_fill_csr(const int* __restrict__ src, const int* __restrict__ dst,
                           const float* __restrict__ dinv, int* __restrict__ cursor,
                           int2* __restrict__ csr_ent, int E) {
  int e = blockIdx.x * blockDim.x + threadIdx.x;
  if (e < E) {
    int d = dst[e];
    int s = src[e];
    int pos = atomicAdd(&cursor[d], 1);
    float nrm = dinv[s] * dinv[d];
    csr_ent[pos] = make_int2(s, __float_as_int(nrm));
  }
}

// x[N][F] fp32 -> xb[N][Fp] bf16, zero-padded cols
__global__ void k_cvt_pad(const float* __restrict__ in, unsigned short* __restrict__ out,
                          int N, int F, int Fp) {
  int idx = blockIdx.x * blockDim.x + threadIdx.x;
  int perRow = Fp >> 3;
  int row = idx / perRow;
  int c = (idx - row * perRow) << 3;
  if (row >= N) return;
  unsigned short o[8];
  if (c + 8 <= F) {
    const float* p = in + (size_t)row * F + c;
    #pragma unroll
    for (int e = 0; e < 8; ++e) o[e] = f2b(p[e]);
  } else {
    #pragma unroll
    for (int e = 0; e < 8; ++e) {
      int cc = c + e;
      o[e] = (cc < F) ? f2b(in[(size_t)row * F + cc]) : (unsigned short)0;
    }
  }
  *(short8*)(out + (size_t)row * Fp + c) = *(short8*)o;
}

// all 8 weights: W[K][Nd] fp32 -> Wt[Ndp][Kp] bf16 (transposed, zero-padded)
struct WtPack {
  const float* W[8];
  unsigned short* Wt[8];
  int K[8], Nd[8], Kp[8], Ndp[8];
};

__global__ void k_wt_all(WtPack p) {
  int l = blockIdx.y;
  int idx = blockIdx.x * blockDim.x + threadIdx.x;
  int Kp = p.Kp[l], Ndp = p.Ndp[l];
  if (idx >= Kp * Ndp) return;
  int n = idx / Kp, k = idx - n * Kp;
  unsigned short v = 0;
  if (n < p.Nd[l] && k < p.K[l]) v = f2b(p.W[l][(size_t)k * p.Nd[l] + n]);
  p.Wt[l][idx] = v;
}

// ---------------------------------------------------------------- GEMM
// C[M,Nd] = A[M,Kp] @ Bt^T, A bf16 [M][lda], Bt bf16 [Ndp][Kp], padded.
// 128x128 tile, 4 waves (2x2), BK=32, 4x4 frags of mfma_f32_16x16x32_bf16.
// global_load_lds staging, 2-deep, counted vmcnt across raw barriers.
// Slot-swizzle (slot ^= (row>>1)&3) at global source AND ds_read (R7-proven).
// 1-D grid + bijective XCD-pairing swizzle: the ncol column-blocks sharing one
// 128-row A panel map to the SAME XCD at adjacent within-XCD positions ->
// panel fetched once, re-reads are L2 hits.
// Epilogue: stage C tile through the (now idle) 32KB smem, copy out with
// row-contiguous vector stores (16 lanes = one bf16 row / 32 lanes = one f32 row).
// smem layout (ushort units): As0 @0, As1 @4096, Bs0 @8192, Bs1 @12288.

__global__ __launch_bounds__(256) void gemm_bf16(
    const unsigned short* __restrict__ A,
    const unsigned short* __restrict__ Bt,
    const float* __restrict__ bias,     // nullable, [Nd]
    float* __restrict__ Cf, int ldcf,   // nullable
    unsigned short* __restrict__ Cb, int ldcb,  // nullable
    int M, int Kp, int Nd, int lda, int relu, int nx, int ncol) {
  __shared__ __attribute__((aligned(16))) unsigned short smem[16384];  // 32KB

  // ---- XCD-pairing block swizzle (bijective incl. tail)
  int bx, by;
  {
    int id = blockIdx.x;
    int nfull = (nx >> 3) << 3;        // rows handled by the swizzled region
    int cut = nfull * ncol;
    if (id < cut) {
      int j = id >> 3;                 // within-XCD sequence index
      int k = id & 7;                  // XCD (round-robin assumption)
      int q = j / ncol;
      bx = k + 8 * q;
      by = j - ncol * q;
    } else {
      int r = id - cut;
      bx = nfull + r / ncol;
      by = r - ncol * (r / ncol);
    }
  }
  const int bm = bx * 128;
  const int bn = by * 128;
  const int tid = threadIdx.x;
  const int wid = tid >> 6;
  const int lane = tid & 63;

  const unsigned short* srcA[2];
  const unsigned short* srcB[2];
  #pragma unroll
  for (int j = 0; j < 2; ++j) {
    int chunk = wid * 2 + j;
    int r_st = chunk * 16 + (lane >> 2);
    int slot = lane & 3;
    int sw = slot ^ ((r_st >> 1) & 3);
    int gm = bm + r_st; if (gm > M - 1) gm = M - 1;   // clamp: dup rows unused
    srcA[j] = A + (size_t)gm * lda + sw * 8;
    int gn = bn + r_st;                                // < Ndp (padded)
    srcB[j] = Bt + (size_t)gn * Kp + sw * 8;
  }

  const int wr = wid >> 1, wc = wid & 1;
  const int lrow = lane & 15;
  const int kgrp = lane >> 4;
  const int rA = wr * 64 + lrow;
  const int rB = wc * 64 + lrow;
  const int aoff = rA * 32 + (kgrp ^ ((rA >> 1) & 3)) * 8;
  const int boff = rB * 32 + (kgrp ^ ((rB >> 1) & 3)) * 8;

  f32x4 acc[4][4];
  #pragma unroll
  for (int i = 0; i < 4; ++i)
    #pragma unroll
    for (int j = 0; j < 4; ++j) acc[i][j] = (f32x4){0.f, 0.f, 0.f, 0.f};

  auto stage = [&](int buf, int k0) {
    unsigned short* As = smem + buf * 4096;
    unsigned short* Bs = smem + 8192 + buf * 4096;
    #pragma unroll
    for (int j = 0; j < 2; ++j) {
      int chunk = wid * 2 + j;
      gload16(srcA[j] + k0, As + chunk * 512);
      gload16(srcB[j] + k0, Bs + chunk * 512);
    }
  };

  const int nt = Kp >> 5;
  stage(0, 0);
  if (nt > 1) stage(1, 32);
  int cur = 0;
  for (int t = 0; t < nt; ++t) {
    if (t + 1 < nt) asm volatile("s_waitcnt vmcnt(4)\n\ts_barrier" ::: "memory");
    else            asm volatile("s_waitcnt vmcnt(0)\n\ts_barrier" ::: "memory");

    const unsigned short* pA = smem + cur * 4096 + aoff;
    const unsigned short* pB = smem + 8192 + cur * 4096 + boff;
    short8 a[4], b[4];
    #pragma unroll
    for (int mi = 0; mi < 4; ++mi) a[mi] = *(const short8*)(pA + mi * 512);
    #pragma unroll
    for (int nj = 0; nj < 4; ++nj) b[nj] = *(const short8*)(pB + nj * 512);

    asm volatile("s_waitcnt lgkmcnt(0)\n\ts_barrier" ::: "memory");
    __builtin_amdgcn_sched_barrier(0);

    if (t + 2 < nt) stage(cur, (t + 2) * 32);

    #pragma unroll
    for (int mi = 0; mi < 4; ++mi)
      #pragma unroll
      for (int nj = 0; nj < 4; ++nj)
        acc[mi][nj] = __builtin_amdgcn_mfma_f32_16x16x32_bf16(a[mi], b[nj], acc[mi][nj], 0, 0, 0);
    cur ^= 1;
  }
  // After the loop: no outstanding DMA (vmcnt(0) waited at last iter), and the
  // last lgkmcnt(0)+barrier retired every wave's ds_reads -> smem reusable.

  float bv[4];
  #pragma unroll
  for (int nj = 0; nj < 4; ++nj) {
    int gn = bn + wc * 64 + nj * 16 + lrow;
    bv[nj] = (bias && gn < Nd) ? bias[gn] : 0.f;
  }

  if (Cb && Nd >= 128) {
    // bf16 C tile [128][128] = 32KB, staged in smem, coalesced copy-out.
    unsigned short* Lb = smem;
    #pragma unroll
    for (int mi = 0; mi < 4; ++mi)
      #pragma unroll
      for (int rr = 0; rr < 4; ++rr) {
        int row = wr * 64 + mi * 16 + 4 * kgrp + rr;
        #pragma unroll
        for (int nj = 0; nj < 4; ++nj) {
          float v = acc[mi][nj][rr] + bv[nj];
          if (relu) v = fmaxf(v, 0.f);
          Lb[row * 128 + wc * 64 + nj * 16 + lrow] = f2b(v);
        }
      }
    __syncthreads();
    #pragma unroll
    for (int c = 0; c < 8; ++c) {
      int g = c * 256 + tid;
      int r = g >> 4, cc = g & 15;        // 16 lanes = one full 256B row
      int gm = bm + r;
      if (gm < M)
        *(short8*)(Cb + (size_t)gm * ldcb + bn + cc * 8) =
            *(const short8*)(Lb + r * 128 + cc * 8);
    }
  } else if (Cf && Nd >= 128) {
    // fp32 C tile staged in two 64-row passes ([64][128] f32 = 32KB).
    float* Lf = (float*)smem;
    #pragma unroll
    for (int p = 0; p < 2; ++p) {
      if (wr == p) {
        #pragma unroll
        for (int mi = 0; mi < 4; ++mi)
          #pragma unroll
          for (int rr = 0; rr < 4; ++rr) {
            int row = mi * 16 + 4 * kgrp + rr;   // 0..63 within half
            #pragma unroll
            for (int nj = 0; nj < 4; ++nj) {
              float v = acc[mi][nj][rr] + bv[nj];
              if (relu) v = fmaxf(v, 0.f);
              Lf[row * 128 + wc * 64 + nj * 16 + lrow] = v;
            }
          }
      }
      __syncthreads();
      #pragma unroll
      for (int c = 0; c < 8; ++c) {
        int g = c * 256 + tid;
        int r = g >> 5, cc = g & 31;      // 32 lanes = one full 512B row
        int gm = bm + p * 64 + r;
        int col = bn + cc * 4;
        if (gm < M) {
          const float* sp = Lf + r * 128 + cc * 4;
          if (col + 4 <= Nd) {
            __builtin_nontemporal_store(*(const f32x4*)sp,
                                        (f32x4*)(Cf + (size_t)gm * ldcf + col));
          } else {
            #pragma unroll
            for (int e = 0; e < 4; ++e)
              if (col + e < Nd) Cf[(size_t)gm * ldcf + col + e] = sp[e];
          }
        }
      }
      __syncthreads();
    }
  } else {
    // narrow-Nd scalar path (zen, Nd=10)
    const int orow = bm + wr * 64;
    const int ocol = bn + wc * 64;
    #pragma unroll
    for (int mi = 0; mi < 4; ++mi) {
      #pragma unroll
      for (int rr = 0; rr < 4; ++rr) {
        int gm = orow + mi * 16 + 4 * kgrp + rr;
        if (gm >= M) continue;
        #pragma unroll
        for (int nj = 0; nj < 4; ++nj) {
          int gn = ocol + nj * 16 + lrow;
          if (gn >= Nd) continue;
          float v = acc[mi][nj][rr] + bv[nj];
          if (relu) v = fmaxf(v, 0.f);
          if (Cf) Cf[(size_t)gm * ldcf + gn] = v;
          if (Cb) Cb[(size_t)gm * ldcb + gn] = f2b(v);
        }
      }
    }
  }
}

// ---------------------------------------------------------------- aggregation
// Wave per node; two 32-lane halves, each gathers its own edges at 16B/lane.
// 16 edges per main trip (8 per half). Fused int2 CSR entries, NT-loaded.
// Cross-half combine via shfl_xor(32). half0 stores bf16 mirror; half1 fp32 NT.

__global__ __launch_bounds__(256) void agg_wave(
    const unsigned short* __restrict__ h,
    const int* __restrict__ row_start, const int2* __restrict__ csr_ent,
    const float* __restrict__ dinv,
    const float* __restrict__ bias,      // nullable
    float* __restrict__ Of,              // nullable
    unsigned short* __restrict__ Ob,     // nullable
    int N, int relu) {
  const int w = threadIdx.x >> 6;
  const int lane = threadIdx.x & 63;
  const int i = blockIdx.x * 4 + w;
  if (i >= N) return;
  const int half = lane >> 5;
  const int hl = lane & 31;
  const int f0 = hl * 8;

  float acc[8];
  if (half == 0) {
    float sn = dinv[i]; sn *= sn;
    short8 hv = *(const short8*)(h + ((size_t)i << 8) + f0);
    #pragma unroll
    for (int j = 0; j < 8; ++j) acc[j] = b2f(((const unsigned short*)&hv)[j]) * sn;
  } else if (bias) {
    #pragma unroll
    for (int j = 0; j < 8; ++j) acc[j] = bias[f0 + j];
  } else {
    #pragma unroll
    for (int j = 0; j < 8; ++j) acc[j] = 0.f;
  }

  int s = row_start[i];
  const int s1 = row_start[i + 1];

  // main: 16 edges per trip (8 per half) -> 8 gathers in flight per lane
  for (; s + 16 <= s1; s += 16) {
    long long pe[8];
    #pragma unroll
    for (int k = 0; k < 8; ++k)
      pe[k] = __builtin_nontemporal_load((const long long*)(csr_ent + s + 2 * k + half));
    short8 ve[8];
    #pragma unroll
    for (int k = 0; k < 8; ++k)
      ve[k] = *(const short8*)(h + ((size_t)(int)pe[k] << 8) + f0);
    #pragma unroll
    for (int k = 0; k < 8; ++k) {
      float wt = i2f((int)(pe[k] >> 32));
      #pragma unroll
      for (int j = 0; j < 8; ++j)
        acc[j] = fmaf(b2f(((const unsigned short*)&ve[k])[j]), wt, acc[j]);
    }
  }
  // 8 edges (4 per half)
  for (; s + 8 <= s1; s += 8) {
    long long pe[4];
    #pragma unroll
    for (int k = 0; k < 4; ++k)
      pe[k] = __builtin_nontemporal_load((const long long*)(csr_ent + s + 2 * k + half));
    short8 ve[4];
    #pragma unroll
    for (int k = 0; k < 4; ++k)
      ve[k] = *(const short8*)(h + ((size_t)(int)pe[k] << 8) + f0);
    #pragma unroll
    for (int k = 0; k < 4; ++k) {
      float wt = i2f((int)(pe[k] >> 32));
      #pragma unroll
      for (int j = 0; j < 8; ++j)
        acc[j] = fmaf(b2f(((const unsigned short*)&ve[k])[j]), wt, acc[j]);
    }
  }
  // 4 edges (2 per half)
  for (; s + 4 <= s1; s += 4) {
    long long p0 = __builtin_nontemporal_load((const long long*)(csr_ent + s + half));
    long long p1 = __builtin_nontemporal_load((const long long*)(csr_ent + s + 2 + half));
    short8 v0 = *(const short8*)(h + ((size_t)(int)p0 << 8) + f0);
    short8 v1 = *(const short8*)(h + ((size_t)(int)p1 << 8) + f0);
    float w0 = i2f((int)(p0 >> 32)), w1 = i2f((int)(p1 >> 32));
    #pragma unroll
    for (int j = 0; j < 8; ++j)
      acc[j] = fmaf(b2f(((const unsigned short*)&v0)[j]), w0, acc[j]);
    #pragma unroll
    for (int j = 0; j < 8; ++j)
      acc[j] = fmaf(b2f(((const unsigned short*)&v1)[j]), w1, acc[j]);
  }
  // predicated pairs
  for (; s < s1; s += 2) {
    int e = s + half;
    bool valid = e < s1;
    long long p0 = valid
        ? __builtin_nontemporal_load((const long long*)(csr_ent + e)) : 0ll;
    short8 vv = *(const short8*)(h + ((size_t)(int)p0 << 8) + f0);
    float wt = i2f((int)(p0 >> 32));
    #pragma unroll
    for (int j = 0; j < 8; ++j)
      acc[j] = fmaf(b2f(((const unsigned short*)&vv)[j]), wt, acc[j]);
  }

  #pragma unroll
  for (int j = 0; j < 8; ++j) acc[j] += __shfl_xor(acc[j], 32, 64);
  if (relu) {
    #pragma unroll
    for (int j = 0; j < 8; ++j) acc[j] = fmaxf(acc[j], 0.f);
  }

  size_t o = ((size_t)i << 8) + f0;
  if (half == 0) {
    if (Ob) {
      unsigned short ob[8];
      #pragma unroll
      for (int j = 0; j < 8; ++j) ob[j] = f2b(acc[j]);
      *(short8*)(Ob + o) = *(short8*)ob;
    }
  } else if (Of) {
    f32x4 lo = {acc[0], acc[1], acc[2], acc[3]};
    f32x4 hi = {acc[4], acc[5], acc[6], acc[7]};
    __builtin_nontemporal_store(lo, (f32x4*)(Of + o));
    __builtin_nontemporal_store(hi, (f32x4*)(Of + o + 4));
  }
}

// Code-path aggregation (CD=10), rows stored with ld=12 (24B, 8B-aligned).
template <int CD>
__global__ void agg_code(
    const unsigned short* __restrict__ h,    // ld 12
    const int* __restrict__ row_start, const int2* __restrict__ csr_ent,
    const float* __restrict__ dinv,
    const float* __restrict__ bias,          // nullable
    float* __restrict__ Of,                  // nullable, ld CD (NT)
    unsigned short* __restrict__ Ob,         // nullable, ld ldo (zero-padded)
    int ldo, int N) {
  const int i = blockIdx.x * blockDim.x + threadIdx.x;
  if (i >= N) return;
  float acc[CD];
  float sn = dinv[i]; sn *= sn;
  {
    const unsigned short* hi = h + (size_t)i * 12;
    uint2 d0 = *(const uint2*)hi;
    uint2 d1 = *(const uint2*)(hi + 4);
    unsigned int d2 = *(const unsigned int*)(hi + 8);
    float t[10];
    up2(d0.x, t[0], t[1]); up2(d0.y, t[2], t[3]);
    up2(d1.x, t[4], t[5]); up2(d1.y, t[6], t[7]);
    up2(d2,   t[8], t[9]);
    #pragma unroll
    for (int f = 0; f < CD; ++f) acc[f] = t[f] * sn + (bias ? bias[f] : 0.f);
  }
  const int s1 = row_start[i + 1];
  for (int s = row_start[i]; s < s1; ++s) {
    long long p = __builtin_nontemporal_load((const long long*)(csr_ent + s));
    const unsigned short* hsr = h + (size_t)(int)p * 12;
    float wgt = i2f((int)(p >> 32));
    uint2 d0 = *(const uint2*)hsr;
    uint2 d1 = *(const uint2*)(hsr + 4);
    unsigned int d2 = *(const unsigned int*)(hsr + 8);
    float t[10];
    up2(d0.x, t[0], t[1]); up2(d0.y, t[2], t[3]);
    up2(d1.x, t[4], t[5]); up2(d1.y, t[6], t[7]);
    up2(d2,   t[8], t[9]);
    #pragma unroll
    for (int f = 0; f < CD; ++f) acc[f] = fmaf(t[f], wgt, acc[f]);
  }
  if (Of) {
    #pragma unroll
    for (int f = 0; f < CD; ++f)
      __builtin_nontemporal_store(acc[f], &Of[(size_t)i * CD + f]);
  }
  if (Ob) {
    #pragma unroll
    for (int f = 0; f < CD; ++f) Ob[(size_t)i * ldo + f] = f2b(acc[f]);
    for (int f = CD; f < ldo; ++f) Ob[(size_t)i * ldo + f] = 0;
  }
}

// ---------------------------------------------------------------- driver

extern "C" void kernel_launch(void* const* d_in, const int* in_sizes, int n_in,
                              void* d_out, int out_size, void* d_ws, size_t ws_size,
                              hipStream_t stream) {
  const float* x   = (const float*)d_in[0];
  const int*   src = (const int*)d_in[1];
  const int*   dst = (const int*)d_in[2];
  const float* Wp[8];
  const float* bp[8];
  for (int i = 0; i < 8; ++i) {
    Wp[i] = (const float*)d_in[3 + 2 * i];
    bp[i] = (const float*)d_in[4 + 2 * i];
  }

  const int H = in_sizes[4];
  const int F = in_sizes[3] / H;
  const int N = in_sizes[0] / F;
  const int E = in_sizes[1];
  const int C = in_sizes[10];   // = 10

  const int Fp = (F + 31) & ~31;           // 512
  const int Cp = (C + 31) & ~31;           // 32
  const int dims[8][2] = { {F,H},{H,H},{H,H},{H,C},{C,H},{H,H},{H,H},{H,F} };

  // ---- workspace layout (256B aligned)
  char* ws = (char*)d_ws;
  size_t off = 0;
  auto alloc = [&](size_t bytes) {
    void* p = ws + off;
    off += (bytes + 255) & ~(size_t)255;
    return p;
  };
  int*   deg       = (int*)alloc((size_t)N * 4);
  int*   row_start = (int*)alloc((size_t)(N + 1) * 4);
  int*   cursor    = (int*)alloc((size_t)N * 4);
  float* dinv      = (float*)alloc((size_t)N * 4);
  int*   part      = (int*)alloc(1024 * 4);
  int2*  csr_ent   = (int2*)alloc((size_t)E * 8);
  unsigned short* xb = (unsigned short*)alloc((size_t)N * Fp * 2);
  WtPack wp;
  for (int i = 0; i < 8; ++i) {
    wp.W[i] = Wp[i];
    wp.K[i] = dims[i][0];
    wp.Nd[i] = dims[i][1];
    wp.Kp[i] = (dims[i][0] + 31) & ~31;
    wp.Ndp[i] = (dims[i][1] + 127) & ~127;
    wp.Wt[i] = (unsigned short*)alloc((size_t)wp.Ndp[i] * wp.Kp[i] * 2);
  }
  unsigned short* hb   = (unsigned short*)alloc((size_t)N * H * 2);
  unsigned short* actP = (unsigned short*)alloc((size_t)N * H * 2);
  unsigned short* actQ = (unsigned short*)alloc((size_t)N * H * 2);
  unsigned short* zpre = (unsigned short*)alloc((size_t)N * 12 * 2);
  unsigned short* zenb = (unsigned short*)alloc((size_t)N * 12 * 2);
  unsigned short* zagg = (unsigned short*)alloc((size_t)N * Cp * 2);
  (void)ws_size;

  // ---- d_out: x_de[N,F] | enc_h1[N,H] | enc_h2[N,H] | enc_h3[N,H] | z_en[N,C]
  float* out_f  = (float*)d_out;
  float* o_xde  = out_f;
  float* o_enc1 = out_f + (size_t)N * F;
  float* o_enc2 = o_enc1 + (size_t)N * H;
  float* o_enc3 = o_enc2 + (size_t)N * H;
  float* o_zen  = o_enc3 + (size_t)N * H;

  const int T = 256;
  const int nb = (N + 255) / 256;
  // ---- graph preprocessing
  k_zero_int<<<(N + T - 1) / T, T, 0, stream>>>(deg, N);
  k_deg<<<(E + T - 1) / T, T, 0, stream>>>(dst, deg, E);
  k_scan1<<<nb, 256, 0, stream>>>(deg, part, N);
  k_scan2<<<1, 1024, 0, stream>>>(part, nb);
  k_scan3<<<nb, 256, 0, stream>>>(deg, part, row_start, cursor, dinv, N);
  k_fill_csr<<<(E + T - 1) / T, T, 0, stream>>>(src, dst, dinv, cursor, csr_ent, E);
  // ---- conversions
  {
    int nth = N * (Fp >> 3);
    k_cvt_pad<<<(nth + T - 1) / T, T, 0, stream>>>(x, xb, N, F, Fp);
    int maxElems = 0;
    for (int i = 0; i < 8; ++i) {
      int e = wp.Kp[i] * wp.Ndp[i];
      if (e > maxElems) maxElems = e;
    }
    dim3 g((maxElems + T - 1) / T, 8);
    k_wt_all<<<g, T, 0, stream>>>(wp);
  }

  const int nx = (N + 127) / 128;
  auto gemm = [&](const unsigned short* A, int lda, int widx, const float* bias,
                  float* Cf, int ldcf, unsigned short* Cb, int ldcb,
                  int Nd, int relu) {
    int ncol = (Nd + 127) / 128;
    gemm_bf16<<<nx * ncol, 256, 0, stream>>>(A, wp.Wt[widx], bias, Cf, ldcf,
                                             Cb, ldcb, N, wp.Kp[widx], Nd, lda,
                                             relu, nx, ncol);
  };
  auto agg256 = [&](const unsigned short* h, const float* bias, float* Of,
                    unsigned short* Ob, int relu) {
    agg_wave<<<(N + 3) / 4, 256, 0, stream>>>(h, row_start, csr_ent,
                                              dinv, bias, Of, Ob, N, relu);
  };

  // enc1: h = xb @ W0 ; enc_h1 = relu(agg(h)+b0)
  gemm(xb, Fp, 0, nullptr, nullptr, 0, hb, H, H, 0);
  agg256(hb, bp[0], o_enc1, actP, 1);
  // enc2
  gemm(actP, H, 1, nullptr, nullptr, 0, hb, H, H, 0);
  agg256(hb, bp[1], o_enc2, actQ, 1);
  // enc3
  gemm(actQ, H, 2, nullptr, nullptr, 0, hb, H, H, 0);
  agg256(hb, bp[2], o_enc3, actP, 1);
  // zen: zpre = enc_h3 @ W3 (ld 12) ; z_en = agg(zpre) + b3
  gemm(actP, H, 3, nullptr, nullptr, 0, zpre, 12, C, 0);
  agg_code<10><<<(N + T - 1) / T, T, 0, stream>>>(
      zpre, row_start, csr_ent, dinv, bp[3], o_zen, zenb, 12, N);
  // dec1 (linearity): zagg = agg_nobias(z_en) ; d1 = relu(zagg @ W4 + b4)
  agg_code<10><<<(N + T - 1) / T, T, 0, stream>>>(
      zenb, row_start, csr_ent, dinv, nullptr, nullptr, zagg, Cp, N);
  gemm(zagg, Cp, 4, bp[4], nullptr, 0, actQ, H, H, 1);
  // dec2
  gemm(actQ, H, 5, nullptr, nullptr, 0, hb, H, H, 0);
  agg256(hb, bp[5], nullptr, actP, 1);
  // dec3
  gemm(actP, H, 6, nullptr, nullptr, 0, hb, H, H, 0);
  agg256(hb, bp[6], nullptr, actQ, 1);
  // xde (linearity): dagg = agg_nobias(d3) ; x_de = dagg @ W7 + b7 (fp32)
  agg256(actQ, nullptr, nullptr, actP, 0);
  gemm(actP, H, 7, bp[7], o_xde, F, nullptr, 0, F, 0);
}